// Round 1
// baseline (312.620 us; speedup 1.0000x reference)
//
#include <hip/hip_runtime.h>
#include <stdint.h>

typedef __attribute__((ext_vector_type(8))) short bf16x8;
typedef __attribute__((ext_vector_type(4))) float f32x4;

__device__ __forceinline__ ushort f2bf(float f) {
  union { float f; uint32_t u; } c; c.f = f;
  uint32_t r = (c.u + 0x7fffu + ((c.u >> 16) & 1u)) >> 16;
  return (ushort)r;
}

__device__ __forceinline__ void gload16(const void* g, void* l) {
  __builtin_amdgcn_global_load_lds(
      (const __attribute__((address_space(1))) void*)g,
      (__attribute__((address_space(3))) void*)l, 16, 0, 0);
}

// ---------------- LayerNorm: fp32 row(1024) -> bf16 ----------------
__global__ __launch_bounds__(256) void ln_kernel(
    const float* __restrict__ x, const float* __restrict__ g,
    const float* __restrict__ bta, ushort* __restrict__ out) {
  const int row = blockIdx.x;
  const int t = threadIdx.x;
  const float4 v = ((const float4*)(x + (size_t)row * 1024))[t];
  float s  = v.x + v.y + v.z + v.w;
  float s2 = v.x*v.x + v.y*v.y + v.z*v.z + v.w*v.w;
  #pragma unroll
  for (int off = 1; off < 64; off <<= 1) {
    s  += __shfl_xor(s,  off);
    s2 += __shfl_xor(s2, off);
  }
  __shared__ float red[8];
  const int wave = t >> 6, lane = t & 63;
  if (lane == 0) { red[wave*2] = s; red[wave*2+1] = s2; }
  __syncthreads();
  s  = red[0] + red[2] + red[4] + red[6];
  s2 = red[1] + red[3] + red[5] + red[7];
  const float mu = s * (1.0f/1024.0f);
  const float var = s2 * (1.0f/1024.0f) - mu*mu;
  const float rs = rsqrtf(var + 1e-6f);
  const float4 gg = ((const float4*)g)[t];
  const float4 bb = ((const float4*)bta)[t];
  ushort4 o;
  o.x = f2bf((v.x - mu) * rs * gg.x + bb.x);
  o.y = f2bf((v.y - mu) * rs * gg.y + bb.y);
  o.z = f2bf((v.z - mu) * rs * gg.z + bb.z);
  o.w = f2bf((v.w - mu) * rs * gg.w + bb.w);
  ((ushort4*)(out + (size_t)row * 1024))[t] = o;
}

// ---------------- fp32 -> bf16 cast (x4 vectorized) ----------------
__global__ __launch_bounds__(256) void cast_bf16_kernel(
    const float* __restrict__ in, ushort* __restrict__ out, int n4) {
  const int i = blockIdx.x * 256 + threadIdx.x;
  if (i >= n4) return;
  const float4 v = ((const float4*)in)[i];
  ushort4 o;
  o.x = f2bf(v.x); o.y = f2bf(v.y); o.z = f2bf(v.z); o.w = f2bf(v.w);
  ((ushort4*)out)[i] = o;
}

// ---------------- GEMM: C[M,N] = A[M,K] * W[N,K]^T (bf16 in, bf16 or f32+resid out)
// 128x128 tile, BK=32, 4 waves, global_load_lds staging (m97 structure).
template<bool RESID>
__global__ __launch_bounds__(256) void gemm_bt(
    const ushort* __restrict__ A, const ushort* __restrict__ W,
    ushort* __restrict__ Cb, float* __restrict__ Cf,
    const float* __restrict__ resid, int M, int N, int K) {
  __shared__ ushort As[128 * 32];
  __shared__ ushort Bs[128 * 32];
  const int t = threadIdx.x;
  const int lane = t & 63, wave = t >> 6;
  const int wr = wave >> 1, wc = wave & 1;
  const int lr = lane & 15, lg = lane >> 4;
  const int brow = blockIdx.y * 128, bcol = blockIdx.x * 128;
  f32x4 acc[4][4] = {};
  const ushort* gA = A + (size_t)(brow + (t >> 2)) * K + (t & 3) * 8;
  const ushort* gB = W + (size_t)(bcol + (t >> 2)) * K + (t & 3) * 8;
  char* la = (char*)As + wave * 1024;
  char* lb = (char*)Bs + wave * 1024;
  for (int k0 = 0; k0 < K; k0 += 32) {
    __syncthreads();
    gload16(gA + k0,                   la);
    gload16(gA + k0 + (size_t)64 * K,  la + 4096);
    gload16(gB + k0,                   lb);
    gload16(gB + k0 + (size_t)64 * K,  lb + 4096);
    __syncthreads();
    bf16x8 af[4], bfr[4];
    #pragma unroll
    for (int i = 0; i < 4; i++)
      af[i]  = *(const bf16x8*)&As[(wr*64 + i*16 + lr) * 32 + lg*8];
    #pragma unroll
    for (int i = 0; i < 4; i++)
      bfr[i] = *(const bf16x8*)&Bs[(wc*64 + i*16 + lr) * 32 + lg*8];
    #pragma unroll
    for (int mi = 0; mi < 4; mi++)
      #pragma unroll
      for (int ni = 0; ni < 4; ni++)
        acc[mi][ni] = __builtin_amdgcn_mfma_f32_16x16x32_bf16(
            af[mi], bfr[ni], acc[mi][ni], 0, 0, 0);
  }
  #pragma unroll
  for (int mi = 0; mi < 4; mi++) {
    #pragma unroll
    for (int ni = 0; ni < 4; ni++) {
      #pragma unroll
      for (int r = 0; r < 4; r++) {
        const size_t row = brow + wr*64 + mi*16 + lg*4 + r;
        const size_t col = bcol + wc*64 + ni*16 + lr;
        if (RESID) Cf[row * N + col] = acc[mi][ni][r] + resid[row * N + col];
        else       Cb[row * N + col] = f2bf(acc[mi][ni][r]);
      }
    }
  }
}

// ---------------- Flash attention: per (qblock64, head, batch) ----------------
__global__ __launch_bounds__(256) void flash_attn(
    const ushort* __restrict__ Qp, const ushort* __restrict__ Kp,
    const ushort* __restrict__ Vp, const int* __restrict__ mask,
    ushort* __restrict__ AO) {
  const int L = 2048;
  const int qb = blockIdx.x, h = blockIdx.y, b = blockIdx.z;
  const int t = threadIdx.x, lane = t & 63, wave = t >> 6;
  const int lr = lane & 15, lg = lane >> 4;
  __shared__ ushort Ks[64 * 64];          // [kv][d]
  __shared__ ushort Vt[64 * 64];          // transposed: [d][kv]
  __shared__ ushort Pl[4 * 16 * 64];      // per-wave P: [wave][qrow16][kv64]
  const size_t base = (size_t)b * L * 1024 + h * 64;
  const int q0 = qb * 64 + wave * 16;     // this wave's 16 q-rows
  bf16x8 aq[2];
  #pragma unroll
  for (int kt = 0; kt < 2; kt++)
    aq[kt] = *(const bf16x8*)(Qp + base + (size_t)(q0 + lr) * 1024 + kt*32 + lg*8);
  f32x4 accO[4] = {};
  float m_run[4] = {-INFINITY, -INFINITY, -INFINITY, -INFINITY};
  float l_run[4] = {0.f, 0.f, 0.f, 0.f};
  char* kb0 = (char*)Ks + wave * 1024;
  for (int kv0 = 0; kv0 < L; kv0 += 64) {
    __syncthreads();
    // stage K tile (linear, async direct-to-LDS)
    gload16(Kp + base + (size_t)(kv0 +      (t >> 3)) * 1024 + (t & 7) * 8, kb0);
    gload16(Kp + base + (size_t)(kv0 + 32 + (t >> 3)) * 1024 + (t & 7) * 8, kb0 + 4096);
    // stage V transposed (reg-staged)
    #pragma unroll
    for (int i = 0; i < 2; i++) {
      const int row = (t >> 3) + i * 32, cg = t & 7;
      const uint4 val = *(const uint4*)(Vp + base + (size_t)(kv0 + row) * 1024 + cg * 8);
      const ushort* u = (const ushort*)&val;
      #pragma unroll
      for (int j = 0; j < 8; j++) Vt[(cg*8 + j) * 64 + row] = u[j];
    }
    __syncthreads();
    // S = Q K^T  (rows = q, cols = kv)
    f32x4 s[4];
    #pragma unroll
    for (int ni = 0; ni < 4; ni++) {
      f32x4 a = {0.f, 0.f, 0.f, 0.f};
      #pragma unroll
      for (int kt = 0; kt < 2; kt++) {
        bf16x8 bk = *(const bf16x8*)&Ks[(ni*16 + lr) * 64 + kt*32 + lg*8];
        a = __builtin_amdgcn_mfma_f32_16x16x32_bf16(aq[kt], bk, a, 0, 0, 0);
      }
      s[ni] = a;
    }
    // online softmax (each lane owns q-rows lg*4+r, kv-cols ni*16+lr)
    #pragma unroll
    for (int r = 0; r < 4; r++) {
      const int qrow = q0 + lg*4 + r;
      float mx = -INFINITY;
      #pragma unroll
      for (int ni = 0; ni < 4; ni++) {
        const int kvcol = kv0 + ni*16 + lr;
        float vv = s[ni][r] * 0.125f;               // 1/sqrt(64)
        if (mask[(size_t)qrow * L + kvcol] == 0) vv = -1e9f;
        s[ni][r] = vv;
        mx = fmaxf(mx, vv);
      }
      #pragma unroll
      for (int off = 1; off < 16; off <<= 1) mx = fmaxf(mx, __shfl_xor(mx, off));
      const float mnew = fmaxf(m_run[r], mx);
      const float alpha = __expf(m_run[r] - mnew);
      m_run[r] = mnew;
      float ps = 0.f;
      #pragma unroll
      for (int ni = 0; ni < 4; ni++) {
        const float p = __expf(s[ni][r] - mnew);
        ps += p;
        Pl[wave*1024 + (lg*4 + r) * 64 + ni*16 + lr] = f2bf(p);
      }
      l_run[r] = l_run[r] * alpha + ps;
      #pragma unroll
      for (int ni = 0; ni < 4; ni++) accO[ni][r] *= alpha;
    }
    // O += P V   (P from per-wave LDS, V^T from LDS)
    #pragma unroll
    for (int kt = 0; kt < 2; kt++) {
      bf16x8 ap = *(const bf16x8*)&Pl[wave*1024 + lr*64 + kt*32 + lg*8];
      #pragma unroll
      for (int ni = 0; ni < 4; ni++) {
        bf16x8 bv = *(const bf16x8*)&Vt[(ni*16 + lr) * 64 + kt*32 + lg*8];
        accO[ni] = __builtin_amdgcn_mfma_f32_16x16x32_bf16(ap, bv, accO[ni], 0, 0, 0);
      }
    }
  }
  float linv[4];
  #pragma unroll
  for (int r = 0; r < 4; r++) {
    float ls = l_run[r];
    #pragma unroll
    for (int off = 1; off < 16; off <<= 1) ls += __shfl_xor(ls, off);
    linv[r] = 1.0f / ls;
  }
  #pragma unroll
  for (int ni = 0; ni < 4; ni++)
    #pragma unroll
    for (int r = 0; r < 4; r++) {
      const size_t row = (size_t)b * L + q0 + lg*4 + r;
      AO[row * 1024 + h*64 + ni*16 + lr] = f2bf(accO[ni][r] * linv[r]);
    }
}

extern "C" void kernel_launch(void* const* d_in, const int* in_sizes, int n_in,
                              void* d_out, int out_size, void* d_ws, size_t ws_size,
                              hipStream_t stream) {
  const float* q    = (const float*)d_in[0];
  const float* k    = (const float*)d_in[1];
  const float* v    = (const float*)d_in[2];
  const int*   mask = (const int*)d_in[3];
  const float* w_q  = (const float*)d_in[4];
  const float* w_k  = (const float*)d_in[5];
  const float* w_v  = (const float*)d_in[6];
  const float* w_o  = (const float*)d_in[7];
  const float* ln_g = (const float*)d_in[8];
  const float* ln_b = (const float*)d_in[9];
  float* out = (float*)d_out;

  const int M = 4096, D = 1024;        // B*L rows, model dim
  char* ws = (char*)d_ws;
  const size_t MB = (size_t)1 << 20;   // total ws use: 64 MB
  ushort* qn  = (ushort*)(ws + 0*MB);
  ushort* kb  = (ushort*)(ws + 8*MB);
  ushort* vb  = (ushort*)(ws + 16*MB);
  ushort* wqb = (ushort*)(ws + 24*MB);
  ushort* wkb = (ushort*)(ws + 26*MB);
  ushort* wvb = (ushort*)(ws + 28*MB);
  ushort* wob = (ushort*)(ws + 30*MB);
  ushort* Qp  = (ushort*)(ws + 32*MB);
  ushort* Kp  = (ushort*)(ws + 40*MB);
  ushort* Vp  = (ushort*)(ws + 48*MB);
  ushort* AO  = (ushort*)(ws + 56*MB);

  ln_kernel<<<M, 256, 0, stream>>>(q, ln_g, ln_b, qn);
  const int n4x = M * D / 4, n4w = D * D / 4;
  cast_bf16_kernel<<<(n4x + 255) / 256, 256, 0, stream>>>(k,   kb,  n4x);
  cast_bf16_kernel<<<(n4x + 255) / 256, 256, 0, stream>>>(v,   vb,  n4x);
  cast_bf16_kernel<<<(n4w + 255) / 256, 256, 0, stream>>>(w_q, wqb, n4w);
  cast_bf16_kernel<<<(n4w + 255) / 256, 256, 0, stream>>>(w_k, wkb, n4w);
  cast_bf16_kernel<<<(n4w + 255) / 256, 256, 0, stream>>>(w_v, wvb, n4w);
  cast_bf16_kernel<<<(n4w + 255) / 256, 256, 0, stream>>>(w_o, wob, n4w);

  dim3 gg(D / 128, M / 128);
  gemm_bt<false><<<gg, 256, 0, stream>>>(qn, wqb, Qp, nullptr, nullptr, M, D, D);
  gemm_bt<false><<<gg, 256, 0, stream>>>(kb, wkb, Kp, nullptr, nullptr, M, D, D);
  gemm_bt<false><<<gg, 256, 0, stream>>>(vb, wvb, Vp, nullptr, nullptr, M, D, D);

  flash_attn<<<dim3(32, 16, 2), 256, 0, stream>>>(Qp, Kp, Vp, mask, AO);

  gemm_bt<true><<<gg, 256, 0, stream>>>(AO, wob, nullptr, out, q, M, D, D);
}

// Round 2
// 286.002 us; speedup vs baseline: 1.0931x; 1.0931x over previous
//
#include <hip/hip_runtime.h>
#include <stdint.h>

typedef __attribute__((ext_vector_type(8))) short bf16x8;
typedef __attribute__((ext_vector_type(4))) float f32x4;

__device__ __forceinline__ ushort f2bf(float f) {
  union { float f; uint32_t u; } c; c.f = f;
  uint32_t r = (c.u + 0x7fffu + ((c.u >> 16) & 1u)) >> 16;
  return (ushort)r;
}

__device__ __forceinline__ void gload16(const void* g, void* l) {
  __builtin_amdgcn_global_load_lds(
      (const __attribute__((address_space(1))) void*)g,
      (__attribute__((address_space(3))) void*)l, 16, 0, 0);
}

// ---------------- LayerNorm: fp32 row(1024) -> bf16 ----------------
__global__ __launch_bounds__(256) void ln_kernel(
    const float* __restrict__ x, const float* __restrict__ g,
    const float* __restrict__ bta, ushort* __restrict__ out) {
  const int row = blockIdx.x;
  const int t = threadIdx.x;
  const float4 v = ((const float4*)(x + (size_t)row * 1024))[t];
  float s  = v.x + v.y + v.z + v.w;
  float s2 = v.x*v.x + v.y*v.y + v.z*v.z + v.w*v.w;
  #pragma unroll
  for (int off = 1; off < 64; off <<= 1) {
    s  += __shfl_xor(s,  off);
    s2 += __shfl_xor(s2, off);
  }
  __shared__ float red[8];
  const int wave = t >> 6, lane = t & 63;
  if (lane == 0) { red[wave*2] = s; red[wave*2+1] = s2; }
  __syncthreads();
  s  = red[0] + red[2] + red[4] + red[6];
  s2 = red[1] + red[3] + red[5] + red[7];
  const float mu = s * (1.0f/1024.0f);
  const float var = s2 * (1.0f/1024.0f) - mu*mu;
  const float rs = rsqrtf(var + 1e-6f);
  const float4 gg = ((const float4*)g)[t];
  const float4 bb = ((const float4*)bta)[t];
  ushort4 o;
  o.x = f2bf((v.x - mu) * rs * gg.x + bb.x);
  o.y = f2bf((v.y - mu) * rs * gg.y + bb.y);
  o.z = f2bf((v.z - mu) * rs * gg.z + bb.z);
  o.w = f2bf((v.w - mu) * rs * gg.w + bb.w);
  ((ushort4*)(out + (size_t)row * 1024))[t] = o;
}

// ---------------- fp32 -> bf16 casts (fused multi-tensor) ----------------
__global__ __launch_bounds__(256) void cast2_bf16(
    const float* __restrict__ a, const float* __restrict__ b,
    ushort* __restrict__ oa, ushort* __restrict__ ob, int n4) {
  const int i = blockIdx.x * 256 + threadIdx.x;
  if (i >= n4) return;
  const float* in = blockIdx.y ? b : a;
  ushort*     out = blockIdx.y ? ob : oa;
  const float4 v = ((const float4*)in)[i];
  ushort4 o;
  o.x = f2bf(v.x); o.y = f2bf(v.y); o.z = f2bf(v.z); o.w = f2bf(v.w);
  ((ushort4*)out)[i] = o;
}

__global__ __launch_bounds__(256) void cast4_bf16(
    const float* __restrict__ a, const float* __restrict__ b,
    const float* __restrict__ c, const float* __restrict__ d,
    ushort* __restrict__ oa, ushort* __restrict__ ob,
    ushort* __restrict__ oc, ushort* __restrict__ od, int n4) {
  const int i = blockIdx.x * 256 + threadIdx.x;
  if (i >= n4) return;
  const float* in; ushort* out;
  switch (blockIdx.y) {
    case 0:  in = a; out = oa; break;
    case 1:  in = b; out = ob; break;
    case 2:  in = c; out = oc; break;
    default: in = d; out = od; break;
  }
  const float4 v = ((const float4*)in)[i];
  ushort4 o;
  o.x = f2bf(v.x); o.y = f2bf(v.y); o.z = f2bf(v.z); o.w = f2bf(v.w);
  ((ushort4*)out)[i] = o;
}

// ---------------- mask tile flags: flags[qt*32+kt] = all-nonzero of 64x64 tile
__global__ __launch_bounds__(256) void mask_flags(
    const int* __restrict__ mask, int* __restrict__ flags) {
  const int qt = blockIdx.y, kt = blockIdx.x;
  const int t = threadIdx.x;
  const int* p = mask + (size_t)(qt * 64 + (t >> 2)) * 2048 + kt * 64 + (t & 3) * 16;
  int ok = 1;
  #pragma unroll
  for (int i = 0; i < 4; i++) {
    const int4 m = ((const int4*)p)[i];
    ok &= (m.x != 0) & (m.y != 0) & (m.z != 0) & (m.w != 0);
  }
  __shared__ int sok;
  if (t == 0) sok = 1;
  __syncthreads();
  if (!ok) atomicAnd(&sok, 0);
  __syncthreads();
  if (t == 0) flags[qt * 32 + kt] = sok;
}

// ---------------- GEMM: C[M,N] = A[M,K] * W[N,K]^T (m97 structure) ----------
template<bool RESID>
__global__ __launch_bounds__(256) void gemm_bt(
    const ushort* __restrict__ A, const ushort* __restrict__ W,
    ushort* __restrict__ Cb, float* __restrict__ Cf,
    const float* __restrict__ resid, int M, int N, int K) {
  __shared__ ushort As[128 * 32];
  __shared__ ushort Bs[128 * 32];
  const int t = threadIdx.x;
  const int lane = t & 63, wave = t >> 6;
  const int wr = wave >> 1, wc = wave & 1;
  const int lr = lane & 15, lg = lane >> 4;
  const int brow = blockIdx.y * 128, bcol = blockIdx.x * 128;
  f32x4 acc[4][4] = {};
  const ushort* gA = A + (size_t)(brow + (t >> 2)) * K + (t & 3) * 8;
  const ushort* gB = W + (size_t)(bcol + (t >> 2)) * K + (t & 3) * 8;
  char* la = (char*)As + wave * 1024;
  char* lb = (char*)Bs + wave * 1024;
  for (int k0 = 0; k0 < K; k0 += 32) {
    __syncthreads();
    gload16(gA + k0,                   la);
    gload16(gA + k0 + (size_t)64 * K,  la + 4096);
    gload16(gB + k0,                   lb);
    gload16(gB + k0 + (size_t)64 * K,  lb + 4096);
    __syncthreads();
    bf16x8 af[4], bfr[4];
    #pragma unroll
    for (int i = 0; i < 4; i++)
      af[i]  = *(const bf16x8*)&As[(wr*64 + i*16 + lr) * 32 + lg*8];
    #pragma unroll
    for (int i = 0; i < 4; i++)
      bfr[i] = *(const bf16x8*)&Bs[(wc*64 + i*16 + lr) * 32 + lg*8];
    #pragma unroll
    for (int mi = 0; mi < 4; mi++)
      #pragma unroll
      for (int ni = 0; ni < 4; ni++)
        acc[mi][ni] = __builtin_amdgcn_mfma_f32_16x16x32_bf16(
            af[mi], bfr[ni], acc[mi][ni], 0, 0, 0);
  }
  #pragma unroll
  for (int mi = 0; mi < 4; mi++) {
    #pragma unroll
    for (int ni = 0; ni < 4; ni++) {
      #pragma unroll
      for (int r = 0; r < 4; r++) {
        const size_t row = brow + wr*64 + mi*16 + lg*4 + r;
        const size_t col = bcol + wc*64 + ni*16 + lr;
        if (RESID) Cf[row * N + col] = acc[mi][ni][r] + resid[row * N + col];
        else       Cb[row * N + col] = f2bf(acc[mi][ni][r]);
      }
    }
  }
}

// ---------------- Flash attention (bank-conflict-swizzled) ----------------
// LDS layouts (all rows are 128 B):
//   Ks [kv][d]: element (row, d-chunk c of 8 bf16) at byte row*128 + ((c<<4) ^ ((row&7)<<4))
//   Vs [d][kv]: element (d, kv)                    at byte d*128  + ((kv*2) ^ ((d&7)<<4))
//   Pl per-wave [q16][kv64]: (q, kv)               at byte q*128  + ((kv*2) ^ ((q&7)<<4))
__global__ __launch_bounds__(256) void flash_attn(
    const ushort* __restrict__ Qp, const ushort* __restrict__ Kp,
    const ushort* __restrict__ Vp, const int* __restrict__ mask,
    const int* __restrict__ tflags, ushort* __restrict__ AO) {
  const int L = 2048;
  const int qb = blockIdx.x, h = blockIdx.y, b = blockIdx.z;
  const int t = threadIdx.x, lane = t & 63, wave = t >> 6;
  const int lr = lane & 15, lg = lane >> 4;
  __shared__ ushort Ks[64 * 64];
  __shared__ ushort Vs[64 * 64];
  __shared__ ushort Pl[4 * 16 * 64];
  const size_t base = (size_t)b * L * 1024 + h * 64;
  const int q0 = qb * 64 + wave * 16;
  const float SC = 0.125f * 1.44269504089f;   // 1/sqrt(64) * log2(e)

  bf16x8 aq[2];
  #pragma unroll
  for (int kt = 0; kt < 2; kt++)
    aq[kt] = *(const bf16x8*)(Qp + base + (size_t)(q0 + lr) * 1024 + kt*32 + lg*8);

  f32x4 accO[4] = {};
  float m_run[4] = {-INFINITY, -INFINITY, -INFINITY, -INFINITY};
  float l_run[4] = {0.f, 0.f, 0.f, 0.f};

  // K staging: pre-swizzled global source so linear LDS dest lands swizzled
  const int r3 = (lane >> 3) & 7;
  const int c3 = (lane & 7) ^ r3;
  const ushort* gK = Kp + base + (size_t)(wave*8 + r3) * 1024 + c3 * 8;
  char* kb0 = (char*)Ks + wave * 1024;

  char* const PlW = (char*)Pl + wave * 2048;

  for (int kv0 = 0, kvt = 0; kv0 < L; kv0 += 64, kvt++) {
    __syncthreads();
    gload16(gK + (size_t)kv0 * 1024,        kb0);
    gload16(gK + (size_t)(kv0 + 32) * 1024, kb0 + 4096);
    // V transposed + swizzled (lanes vary kv -> conflict-free writes)
    #pragma unroll
    for (int i = 0; i < 2; i++) {
      const int cg = wave + i * 4;                       // d-chunk 0..7
      const uint4 val = *(const uint4*)(Vp + base + (size_t)(kv0 + lane) * 1024 + cg * 8);
      const ushort* u = (const ushort*)&val;
      #pragma unroll
      for (int j = 0; j < 8; j++) {
        const int d = cg * 8 + j;
        *(ushort*)((char*)Vs + d * 128 + ((lane * 2) ^ (j << 4))) = u[j];
      }
    }
    __syncthreads();

    // S = Q K^T
    f32x4 s[4];
    #pragma unroll
    for (int ni = 0; ni < 4; ni++) {
      f32x4 a = {0.f, 0.f, 0.f, 0.f};
      #pragma unroll
      for (int kt = 0; kt < 2; kt++) {
        const bf16x8 bk = *(const bf16x8*)((const char*)Ks + (ni*16 + lr) * 128 +
                                           (((kt*4 + lg) ^ (lr & 7)) << 4));
        a = __builtin_amdgcn_mfma_f32_16x16x32_bf16(aq[kt], bk, a, 0, 0, 0);
      }
      s[ni] = a;
    }

    const bool ok = tflags[qb * 32 + kvt] != 0;

    // online softmax (base-2 domain); lane owns q-rows lg*4+r, kv-cols ni*16+lr
    #pragma unroll
    for (int r = 0; r < 4; r++) {
      const int qrow = q0 + lg*4 + r;
      float vv[4];
      #pragma unroll
      for (int ni = 0; ni < 4; ni++) vv[ni] = s[ni][r] * SC;
      if (!ok) {
        #pragma unroll
        for (int ni = 0; ni < 4; ni++)
          if (mask[(size_t)qrow * L + kv0 + ni*16 + lr] == 0) vv[ni] = -1e9f;
      }
      float mx = fmaxf(fmaxf(vv[0], vv[1]), fmaxf(vv[2], vv[3]));
      #pragma unroll
      for (int off = 1; off < 16; off <<= 1) mx = fmaxf(mx, __shfl_xor(mx, off));
      const float mnew = fmaxf(m_run[r], mx);
      const float alpha = exp2f(m_run[r] - mnew);
      m_run[r] = mnew;
      const int q16 = lg*4 + r;
      float ps = 0.f;
      #pragma unroll
      for (int ni = 0; ni < 4; ni++) {
        const float p = exp2f(vv[ni] - mnew);
        ps += p;
        *(ushort*)(PlW + q16 * 128 + (((ni*16 + lr) * 2) ^ ((q16 & 7) << 4))) = f2bf(p);
      }
      l_run[r] = l_run[r] * alpha + ps;
      #pragma unroll
      for (int ni = 0; ni < 4; ni++) accO[ni][r] *= alpha;
    }

    // O += P V
    #pragma unroll
    for (int kt = 0; kt < 2; kt++) {
      const bf16x8 ap = *(const bf16x8*)(PlW + lr * 128 +
                                         ((kt*64 + lg*16) ^ ((lr & 7) << 4)));
      #pragma unroll
      for (int ni = 0; ni < 4; ni++) {
        const bf16x8 bv = *(const bf16x8*)((const char*)Vs + (ni*16 + lr) * 128 +
                                           (((kt*4 + lg) ^ (lr & 7)) << 4));
        accO[ni] = __builtin_amdgcn_mfma_f32_16x16x32_bf16(ap, bv, accO[ni], 0, 0, 0);
      }
    }
  }

  float linv[4];
  #pragma unroll
  for (int r = 0; r < 4; r++) {
    float ls = l_run[r];
    #pragma unroll
    for (int off = 1; off < 16; off <<= 1) ls += __shfl_xor(ls, off);
    linv[r] = 1.0f / ls;
  }
  #pragma unroll
  for (int ni = 0; ni < 4; ni++)
    #pragma unroll
    for (int r = 0; r < 4; r++) {
      const size_t row = (size_t)b * L + q0 + lg*4 + r;
      AO[row * 1024 + h*64 + ni*16 + lr] = f2bf(accO[ni][r] * linv[r]);
    }
}

extern "C" void kernel_launch(void* const* d_in, const int* in_sizes, int n_in,
                              void* d_out, int out_size, void* d_ws, size_t ws_size,
                              hipStream_t stream) {
  const float* q    = (const float*)d_in[0];
  const float* k    = (const float*)d_in[1];
  const float* v    = (const float*)d_in[2];
  const int*   mask = (const int*)d_in[3];
  const float* w_q  = (const float*)d_in[4];
  const float* w_k  = (const float*)d_in[5];
  const float* w_v  = (const float*)d_in[6];
  const float* w_o  = (const float*)d_in[7];
  const float* ln_g = (const float*)d_in[8];
  const float* ln_b = (const float*)d_in[9];
  float* out = (float*)d_out;

  const int M = 4096, D = 1024;
  char* ws = (char*)d_ws;
  const size_t MB = (size_t)1 << 20;
  ushort* qn  = (ushort*)(ws + 0*MB);
  ushort* kb  = (ushort*)(ws + 8*MB);    // dead after gemm-K; flags reuse its head
  ushort* vb  = (ushort*)(ws + 16*MB);
  ushort* wqb = (ushort*)(ws + 24*MB);
  ushort* wkb = (ushort*)(ws + 26*MB);
  ushort* wvb = (ushort*)(ws + 28*MB);
  ushort* wob = (ushort*)(ws + 30*MB);
  ushort* Qp  = (ushort*)(ws + 32*MB);
  ushort* Kp  = (ushort*)(ws + 40*MB);
  ushort* Vp  = (ushort*)(ws + 48*MB);
  ushort* AO  = (ushort*)(ws + 56*MB);
  int* tflags = (int*)(ws + 8*MB);       // 4 KB, written after gemm-K

  ln_kernel<<<M, 256, 0, stream>>>(q, ln_g, ln_b, qn);
  const int n4x = M * D / 4, n4w = D * D / 4;
  cast2_bf16<<<dim3((n4x + 255) / 256, 2), 256, 0, stream>>>(k, v, kb, vb, n4x);
  cast4_bf16<<<dim3((n4w + 255) / 256, 4), 256, 0, stream>>>(
      w_q, w_k, w_v, w_o, wqb, wkb, wvb, wob, n4w);

  dim3 gg(D / 128, M / 128);
  gemm_bt<false><<<gg, 256, 0, stream>>>(qn, wqb, Qp, nullptr, nullptr, M, D, D);
  gemm_bt<false><<<gg, 256, 0, stream>>>(kb, wkb, Kp, nullptr, nullptr, M, D, D);
  gemm_bt<false><<<gg, 256, 0, stream>>>(vb, wvb, Vp, nullptr, nullptr, M, D, D);

  mask_flags<<<dim3(32, 32), 256, 0, stream>>>(mask, tflags);

  flash_attn<<<dim3(32, 16, 2), 256, 0, stream>>>(Qp, Kp, Vp, mask, tflags, AO);

  gemm_bt<true><<<gg, 256, 0, stream>>>(AO, wob, nullptr, out, q, M, D, D);
}

// Round 3
// 247.554 us; speedup vs baseline: 1.2628x; 1.1553x over previous
//
#include <hip/hip_runtime.h>
#include <stdint.h>

typedef __attribute__((ext_vector_type(8))) short bf16x8;
typedef __attribute__((ext_vector_type(4))) short s16x4;
typedef __attribute__((ext_vector_type(4))) float f32x4;

__device__ __forceinline__ ushort f2bf(float f) {
  union { float f; uint32_t u; } c; c.f = f;
  uint32_t r = (c.u + 0x7fffu + ((c.u >> 16) & 1u)) >> 16;
  return (ushort)r;
}

__device__ __forceinline__ void gload16(const void* g, void* l) {
  __builtin_amdgcn_global_load_lds(
      (const __attribute__((address_space(1))) void*)g,
      (__attribute__((address_space(3))) void*)l, 16, 0, 0);
}

__device__ __forceinline__ unsigned lds_addr(const void* p) {
  return (unsigned)(uintptr_t)(__attribute__((address_space(3))) const char*)p;
}

// ---------------- LayerNorm: fp32 row(1024) -> bf16 ----------------
__global__ __launch_bounds__(256) void ln_kernel(
    const float* __restrict__ x, const float* __restrict__ g,
    const float* __restrict__ bta, ushort* __restrict__ out) {
  const int row = blockIdx.x;
  const int t = threadIdx.x;
  const float4 v = ((const float4*)(x + (size_t)row * 1024))[t];
  float s  = v.x + v.y + v.z + v.w;
  float s2 = v.x*v.x + v.y*v.y + v.z*v.z + v.w*v.w;
  #pragma unroll
  for (int off = 1; off < 64; off <<= 1) {
    s  += __shfl_xor(s,  off);
    s2 += __shfl_xor(s2, off);
  }
  __shared__ float red[8];
  const int wave = t >> 6, lane = t & 63;
  if (lane == 0) { red[wave*2] = s; red[wave*2+1] = s2; }
  __syncthreads();
  s  = red[0] + red[2] + red[4] + red[6];
  s2 = red[1] + red[3] + red[5] + red[7];
  const float mu = s * (1.0f/1024.0f);
  const float var = s2 * (1.0f/1024.0f) - mu*mu;
  const float rs = rsqrtf(var + 1e-6f);
  const float4 gg = ((const float4*)g)[t];
  const float4 bb = ((const float4*)bta)[t];
  ushort4 o;
  o.x = f2bf((v.x - mu) * rs * gg.x + bb.x);
  o.y = f2bf((v.y - mu) * rs * gg.y + bb.y);
  o.z = f2bf((v.z - mu) * rs * gg.z + bb.z);
  o.w = f2bf((v.w - mu) * rs * gg.w + bb.w);
  ((ushort4*)(out + (size_t)row * 1024))[t] = o;
}

// ---------------- fp32 -> bf16 casts ----------------
__global__ __launch_bounds__(256) void cast2_bf16(
    const float* __restrict__ a, const float* __restrict__ b,
    ushort* __restrict__ oa, ushort* __restrict__ ob, int n4) {
  const int i = blockIdx.x * 256 + threadIdx.x;
  if (i >= n4) return;
  const float* in = blockIdx.y ? b : a;
  ushort*     out = blockIdx.y ? ob : oa;
  const float4 v = ((const float4*)in)[i];
  ushort4 o;
  o.x = f2bf(v.x); o.y = f2bf(v.y); o.z = f2bf(v.z); o.w = f2bf(v.w);
  ((ushort4*)out)[i] = o;
}

__global__ __launch_bounds__(256) void cast4_bf16(
    const float* __restrict__ a, const float* __restrict__ b,
    const float* __restrict__ c, const float* __restrict__ d,
    ushort* __restrict__ oa, ushort* __restrict__ ob,
    ushort* __restrict__ oc, ushort* __restrict__ od, int n4) {
  const int i = blockIdx.x * 256 + threadIdx.x;
  if (i >= n4) return;
  const float* in; ushort* out;
  switch (blockIdx.y) {
    case 0:  in = a; out = oa; break;
    case 1:  in = b; out = ob; break;
    case 2:  in = c; out = oc; break;
    default: in = d; out = od; break;
  }
  const float4 v = ((const float4*)in)[i];
  ushort4 o;
  o.x = f2bf(v.x); o.y = f2bf(v.y); o.z = f2bf(v.z); o.w = f2bf(v.w);
  ((ushort4*)out)[i] = o;
}

// ---------------- mask tile flags ----------------
__global__ __launch_bounds__(256) void mask_flags(
    const int* __restrict__ mask, int* __restrict__ flags) {
  const int qt = blockIdx.y, kt = blockIdx.x;
  const int t = threadIdx.x;
  const int* p = mask + (size_t)(qt * 64 + (t >> 2)) * 2048 + kt * 64 + (t & 3) * 16;
  int ok = 1;
  #pragma unroll
  for (int i = 0; i < 4; i++) {
    const int4 m = ((const int4*)p)[i];
    ok &= (m.x != 0) & (m.y != 0) & (m.z != 0) & (m.w != 0);
  }
  __shared__ int sok;
  if (t == 0) sok = 1;
  __syncthreads();
  if (!ok) atomicAnd(&sok, 0);
  __syncthreads();
  if (t == 0) flags[qt * 32 + kt] = sok;
}

// ---------------- GEMM: C[M,1024] = A[M,1024] * W[1024,1024]^T ----------------
// 128x128 tile, BK=32, 3-deep counted-vmcnt pipeline, 4 LDS buffers.
// z selects (A,W,C) triple so Q/K/V projections share one launch.
template<bool RESID>
__global__ __launch_bounds__(256) void gemm3(
    const ushort* __restrict__ A0, const ushort* __restrict__ W0, ushort* __restrict__ C0,
    const ushort* __restrict__ A1, const ushort* __restrict__ W1, ushort* __restrict__ C1,
    const ushort* __restrict__ A2, const ushort* __restrict__ W2, ushort* __restrict__ C2,
    float* __restrict__ Cf, const float* __restrict__ resid) {
  __shared__ ushort As[4][4096];
  __shared__ ushort Bs[4][4096];
  const int t = threadIdx.x, lane = t & 63, wave = t >> 6;
  const int wr = wave >> 1, wc = wave & 1;
  const int lr = lane & 15, lg = lane >> 4;
  const int brow = blockIdx.y * 128, bcol = blockIdx.x * 128;
  const int z = blockIdx.z;
  const ushort* A = z == 0 ? A0 : (z == 1 ? A1 : A2);
  const ushort* W = z == 0 ? W0 : (z == 1 ? W1 : W2);
  ushort*      C = z == 0 ? C0 : (z == 1 ? C1 : C2);
  f32x4 acc[4][4] = {};
  const ushort* gA = A + (size_t)(brow + (t >> 2)) * 1024 + (t & 3) * 8;
  const ushort* gB = W + (size_t)(bcol + (t >> 2)) * 1024 + (t & 3) * 8;
  const int woff = wave * 1024;

#define G_ISSUE(S) { \
    char* la = (char*)As + ((S) & 3) * 8192 + woff; \
    char* lb = (char*)Bs + ((S) & 3) * 8192 + woff; \
    const ushort* ap_ = gA + (S) * 32; \
    const ushort* bp_ = gB + (S) * 32; \
    gload16(ap_, la); gload16(ap_ + 64 * 1024, la + 4096); \
    gload16(bp_, lb); gload16(bp_ + 64 * 1024, lb + 4096); }

#define G_COMPUTE(S) { \
    const ushort* as_ = As[(S) & 3]; \
    const ushort* bs_ = Bs[(S) & 3]; \
    bf16x8 af[4], bfr[4]; \
    _Pragma("unroll") for (int i = 0; i < 4; i++) \
      af[i]  = *(const bf16x8*)&as_[(wr*64 + i*16 + lr) * 32 + lg*8]; \
    _Pragma("unroll") for (int i = 0; i < 4; i++) \
      bfr[i] = *(const bf16x8*)&bs_[(wc*64 + i*16 + lr) * 32 + lg*8]; \
    _Pragma("unroll") for (int mi = 0; mi < 4; mi++) \
      _Pragma("unroll") for (int ni = 0; ni < 4; ni++) \
        acc[mi][ni] = __builtin_amdgcn_mfma_f32_16x16x32_bf16(af[mi], bfr[ni], acc[mi][ni], 0, 0, 0); }

  G_ISSUE(0); G_ISSUE(1); G_ISSUE(2);
  for (int s = 0; s < 30; ++s) {
    asm volatile("s_waitcnt vmcnt(8)" ::: "memory");   // own 4 loads of step s landed
    __builtin_amdgcn_s_barrier();                      // all waves' loads landed
    if (s < 29) G_ISSUE(s + 3);                        // into buffer freed at step s-1
    G_COMPUTE(s);
  }
  asm volatile("s_waitcnt vmcnt(4)" ::: "memory");
  __builtin_amdgcn_s_barrier();
  G_COMPUTE(30);
  asm volatile("s_waitcnt vmcnt(0)" ::: "memory");
  __builtin_amdgcn_s_barrier();
  G_COMPUTE(31);
#undef G_ISSUE
#undef G_COMPUTE

  #pragma unroll
  for (int mi = 0; mi < 4; mi++) {
    #pragma unroll
    for (int ni = 0; ni < 4; ni++) {
      #pragma unroll
      for (int r = 0; r < 4; r++) {
        const size_t row = brow + wr*64 + mi*16 + lg*4 + r;
        const size_t col = bcol + wc*64 + ni*16 + lr;
        if (RESID) Cf[row * 1024 + col] = acc[mi][ni][r] + resid[row * 1024 + col];
        else       C [row * 1024 + col] = f2bf(acc[mi][ni][r]);
      }
    }
  }
}

// ---------------- Flash attention ----------------
// K LDS: [kv][d] rows 128B, chunk c at byte row*128 + ((c<<4) ^ ((row&7)<<4)); double-buffered.
// V LDS: 4x16 subtiles, S = (kv/4)*4 + (d/16), subtile byte S*128, elem (r,c) at 2*(r*16+c);
//        staged linearly by global_load_lds (source pre-arranged), read by ds_read_b64_tr_b16.
// P LDS: per-wave [q16][kv64] rows 128B, XOR-swizzled.
__global__ __launch_bounds__(256) void flash_attn(
    const ushort* __restrict__ Qp, const ushort* __restrict__ Kp,
    const ushort* __restrict__ Vp, const int* __restrict__ mask,
    const int* __restrict__ tflags, ushort* __restrict__ AO) {
  const int L = 2048;
  const int qb = blockIdx.x, h = blockIdx.y, b = blockIdx.z;
  const int t = threadIdx.x, lane = t & 63, wave = t >> 6;
  const int lr = lane & 15, lg = lane >> 4;
  __shared__ ushort Ks[2][64 * 64];
  __shared__ ushort Vs[2][64 * 64];
  __shared__ ushort Pl[4][16 * 64];
  const size_t base = (size_t)b * L * 1024 + h * 64;
  const int q0 = qb * 64 + wave * 16;
  const float SC = 0.125f * 1.44269504089f;

  bf16x8 aq[2];
  #pragma unroll
  for (int kt = 0; kt < 2; kt++)
    aq[kt] = *(const bf16x8*)(Qp + base + (size_t)(q0 + lr) * 1024 + kt*32 + lg*8);

  f32x4 accO[4] = {};
  float m_run[4] = {-INFINITY, -INFINITY, -INFINITY, -INFINITY};
  float l_run[4] = {0.f, 0.f, 0.f, 0.f};

  // K staging: pre-swizzled global source, linear LDS dest
  const int r3 = (lane >> 3) & 7;
  const int c3 = (lane & 7) ^ r3;
  const ushort* gK = Kp + base + (size_t)(wave*8 + r3) * 1024 + c3 * 8;
  // V staging: subtile-ordered source, linear LDS dest
  const int sv = t >> 3, hv = t & 7;
  const int vkv = (sv >> 2) * 4 + (hv >> 1);
  const int vd  = (sv & 3) * 16 + (hv & 1) * 8;
  const ushort* gV = Vp + base + (size_t)vkv * 1024 + vd;

  char* const PlW = (char*)Pl + wave * 2048;
  const unsigned vbase = lds_addr((const char*)Vs) + lg * 1024 + lr * 8;

  // stage tile 0
  {
    char* kb0 = (char*)Ks + wave * 1024;
    gload16(gK, kb0);
    gload16(gK + (size_t)32 * 1024, kb0 + 4096);
    char* vb0 = (char*)Vs + wave * 1024;
    gload16(gV, vb0);
    gload16(gV + (size_t)32 * 1024, vb0 + 4096);
  }
  asm volatile("s_waitcnt vmcnt(0)" ::: "memory");
  __builtin_amdgcn_s_barrier();

  for (int kvt = 0; kvt < 32; ++kvt) {
    const int cur = kvt & 1, nxt = cur ^ 1;
    const int kv0 = kvt * 64;
    // prefetch next tile (issue early — completes under this tile's compute)
    if (kvt + 1 < 32) {
      char* kb0 = (char*)Ks + nxt * 8192 + wave * 1024;
      const ushort* gKn = gK + (size_t)(kv0 + 64) * 1024;
      gload16(gKn, kb0);
      gload16(gKn + (size_t)32 * 1024, kb0 + 4096);
      char* vb0 = (char*)Vs + nxt * 8192 + wave * 1024;
      const ushort* gVn = gV + (size_t)(kv0 + 64) * 1024;
      gload16(gVn, vb0);
      gload16(gVn + (size_t)32 * 1024, vb0 + 4096);
    }

    // S = Q K^T
    const char* KsC = (const char*)Ks + cur * 8192;
    f32x4 s[4];
    #pragma unroll
    for (int ni = 0; ni < 4; ni++) {
      f32x4 a = {0.f, 0.f, 0.f, 0.f};
      #pragma unroll
      for (int kt = 0; kt < 2; kt++) {
        const bf16x8 bk = *(const bf16x8*)(KsC + (ni*16 + lr) * 128 +
                                           (((kt*4 + lg) ^ (lr & 7)) << 4));
        a = __builtin_amdgcn_mfma_f32_16x16x32_bf16(aq[kt], bk, a, 0, 0, 0);
      }
      s[ni] = a;
    }

    // issue V tr-reads early: latency hides under softmax
    const unsigned vaddr = vbase + cur * 8192;
    s16x4 vlo[2][4], vhi[2][4];
    #pragma unroll
    for (int kt = 0; kt < 2; kt++) {
      #pragma unroll
      for (int ni = 0; ni < 4; ni++) {
        asm volatile("ds_read_b64_tr_b16 %0, %2 offset:%3\n\t"
                     "ds_read_b64_tr_b16 %1, %2 offset:%4"
                     : "=v"(vlo[kt][ni]), "=v"(vhi[kt][ni])
                     : "v"(vaddr), "i"(kt*4096 + ni*128), "i"(kt*4096 + ni*128 + 512)
                     : "memory");
      }
    }

    const bool ok = tflags[qb * 32 + kvt] != 0;

    // online softmax (base-2); lane owns q-rows lg*4+r, kv-cols ni*16+lr
    #pragma unroll
    for (int r = 0; r < 4; r++) {
      const int qrow = q0 + lg*4 + r;
      float vv[4];
      #pragma unroll
      for (int ni = 0; ni < 4; ni++) vv[ni] = s[ni][r] * SC;
      if (!ok) {
        #pragma unroll
        for (int ni = 0; ni < 4; ni++)
          if (mask[(size_t)qrow * L + kv0 + ni*16 + lr] == 0) vv[ni] = -1e9f;
      }
      float mx = fmaxf(fmaxf(vv[0], vv[1]), fmaxf(vv[2], vv[3]));
      #pragma unroll
      for (int off = 1; off < 16; off <<= 1) mx = fmaxf(mx, __shfl_xor(mx, off));
      const float mnew = fmaxf(m_run[r], mx);
      const float alpha = exp2f(m_run[r] - mnew);
      m_run[r] = mnew;
      const int q16 = lg*4 + r;
      float ps = 0.f;
      #pragma unroll
      for (int ni = 0; ni < 4; ni++) {
        const float p = exp2f(vv[ni] - mnew);
        ps += p;
        *(ushort*)(PlW + q16 * 128 + (((ni*16 + lr) * 2) ^ ((q16 & 7) << 4))) = f2bf(p);
      }
      l_run[r] = l_run[r] * alpha + ps;
      #pragma unroll
      for (int ni = 0; ni < 4; ni++) accO[ni][r] *= alpha;
    }

    // P fragments
    bf16x8 ap[2];
    #pragma unroll
    for (int kt = 0; kt < 2; kt++)
      ap[kt] = *(const bf16x8*)(PlW + lr * 128 + ((kt*64 + lg*16) ^ ((lr & 7) << 4)));

    asm volatile("s_waitcnt lgkmcnt(0)" ::: "memory");
    __builtin_amdgcn_sched_barrier(0);

    // O += P V
    #pragma unroll
    for (int kt = 0; kt < 2; kt++) {
      #pragma unroll
      for (int ni = 0; ni < 4; ni++) {
        const bf16x8 bv = __builtin_shufflevector(vlo[kt][ni], vhi[kt][ni],
                                                  0, 1, 2, 3, 4, 5, 6, 7);
        accO[ni] = __builtin_amdgcn_mfma_f32_16x16x32_bf16(ap[kt], bv, accO[ni], 0, 0, 0);
      }
    }

    asm volatile("s_waitcnt vmcnt(0)" ::: "memory");   // next tile staged
    __builtin_amdgcn_s_barrier();
  }

  float linv[4];
  #pragma unroll
  for (int r = 0; r < 4; r++) {
    float ls = l_run[r];
    #pragma unroll
    for (int off = 1; off < 16; off <<= 1) ls += __shfl_xor(ls, off);
    linv[r] = 1.0f / ls;
  }
  #pragma unroll
  for (int ni = 0; ni < 4; ni++)
    #pragma unroll
    for (int r = 0; r < 4; r++) {
      const size_t row = (size_t)b * L + q0 + lg*4 + r;
      AO[row * 1024 + h*64 + ni*16 + lr] = f2bf(accO[ni][r] * linv[r]);
    }
}

extern "C" void kernel_launch(void* const* d_in, const int* in_sizes, int n_in,
                              void* d_out, int out_size, void* d_ws, size_t ws_size,
                              hipStream_t stream) {
  const float* q    = (const float*)d_in[0];
  const float* k    = (const float*)d_in[1];
  const float* v    = (const float*)d_in[2];
  const int*   mask = (const int*)d_in[3];
  const float* w_q  = (const float*)d_in[4];
  const float* w_k  = (const float*)d_in[5];
  const float* w_v  = (const float*)d_in[6];
  const float* w_o  = (const float*)d_in[7];
  const float* ln_g = (const float*)d_in[8];
  const float* ln_b = (const float*)d_in[9];
  float* out = (float*)d_out;

  const int M = 4096, D = 1024;
  char* ws = (char*)d_ws;
  const size_t MB = (size_t)1 << 20;
  ushort* qn  = (ushort*)(ws + 0*MB);
  ushort* kb  = (ushort*)(ws + 8*MB);
  ushort* vb  = (ushort*)(ws + 16*MB);
  ushort* wqb = (ushort*)(ws + 24*MB);
  ushort* wkb = (ushort*)(ws + 26*MB);
  ushort* wvb = (ushort*)(ws + 28*MB);
  ushort* wob = (ushort*)(ws + 30*MB);
  ushort* Qp  = (ushort*)(ws + 32*MB);
  ushort* Kp  = (ushort*)(ws + 40*MB);
  ushort* Vp  = (ushort*)(ws + 48*MB);
  ushort* AO  = (ushort*)(ws + 56*MB);
  int* tflags = (int*)(ws + 8*MB);       // reuses kb after QKV GEMM consumed it

  ln_kernel<<<M, 256, 0, stream>>>(q, ln_g, ln_b, qn);
  const int n4x = M * D / 4, n4w = D * D / 4;
  cast2_bf16<<<dim3((n4x + 255) / 256, 2), 256, 0, stream>>>(k, v, kb, vb, n4x);
  cast4_bf16<<<dim3((n4w + 255) / 256, 4), 256, 0, stream>>>(
      w_q, w_k, w_v, w_o, wqb, wkb, wvb, wob, n4w);

  gemm3<false><<<dim3(8, 32, 3), 256, 0, stream>>>(
      qn, wqb, Qp, kb, wkb, Kp, vb, wvb, Vp, nullptr, nullptr);

  mask_flags<<<dim3(32, 32), 256, 0, stream>>>(mask, tflags);

  flash_attn<<<dim3(32, 16, 2), 256, 0, stream>>>(Qp, Kp, Vp, mask, tflags, AO);

  gemm3<true><<<dim3(8, 32, 1), 256, 0, stream>>>(
      AO, wob, nullptr, nullptr, nullptr, nullptr, nullptr, nullptr, nullptr, out, q);
}

// Round 4
// 191.085 us; speedup vs baseline: 1.6360x; 1.2955x over previous
//
#include <hip/hip_runtime.h>
#include <stdint.h>

typedef __attribute__((ext_vector_type(8))) short bf16x8;
typedef __attribute__((ext_vector_type(4))) short s16x4;
typedef __attribute__((ext_vector_type(4))) float f32x4;
typedef __attribute__((ext_vector_type(16))) float f32x16;

__device__ __forceinline__ ushort f2bf(float f) {
  union { float f; uint32_t u; } c; c.f = f;
  uint32_t r = (c.u + 0x7fffu + ((c.u >> 16) & 1u)) >> 16;
  return (ushort)r;
}

__device__ __forceinline__ void gload16(const void* g, void* l) {
  __builtin_amdgcn_global_load_lds(
      (const __attribute__((address_space(1))) void*)g,
      (__attribute__((address_space(3))) void*)l, 16, 0, 0);
}

__device__ __forceinline__ unsigned lds_addr(const void* p) {
  return (unsigned)(uintptr_t)(__attribute__((address_space(3))) const char*)p;
}

__device__ __forceinline__ uint32_t cvtpk(float lo, float hi) {
  uint32_t d;
  asm("v_cvt_pk_bf16_f32 %0, %1, %2" : "=v"(d) : "v"(lo), "v"(hi));
  return d;
}

// ---------------- LayerNorm: fp32 row(1024) -> bf16 ----------------
__global__ __launch_bounds__(256) void ln_kernel(
    const float* __restrict__ x, const float* __restrict__ g,
    const float* __restrict__ bta, ushort* __restrict__ out) {
  const int row = blockIdx.x;
  const int t = threadIdx.x;
  const float4 v = ((const float4*)(x + (size_t)row * 1024))[t];
  float s  = v.x + v.y + v.z + v.w;
  float s2 = v.x*v.x + v.y*v.y + v.z*v.z + v.w*v.w;
  #pragma unroll
  for (int off = 1; off < 64; off <<= 1) {
    s  += __shfl_xor(s,  off);
    s2 += __shfl_xor(s2, off);
  }
  __shared__ float red[8];
  const int wave = t >> 6, lane = t & 63;
  if (lane == 0) { red[wave*2] = s; red[wave*2+1] = s2; }
  __syncthreads();
  s  = red[0] + red[2] + red[4] + red[6];
  s2 = red[1] + red[3] + red[5] + red[7];
  const float mu = s * (1.0f/1024.0f);
  const float var = s2 * (1.0f/1024.0f) - mu*mu;
  const float rs = rsqrtf(var + 1e-6f);
  const float4 gg = ((const float4*)g)[t];
  const float4 bb = ((const float4*)bta)[t];
  ushort4 o;
  o.x = f2bf((v.x - mu) * rs * gg.x + bb.x);
  o.y = f2bf((v.y - mu) * rs * gg.y + bb.y);
  o.z = f2bf((v.z - mu) * rs * gg.z + bb.z);
  o.w = f2bf((v.w - mu) * rs * gg.w + bb.w);
  ((ushort4*)(out + (size_t)row * 1024))[t] = o;
}

// ---------------- fp32 -> bf16 casts ----------------
__global__ __launch_bounds__(256) void cast2_bf16(
    const float* __restrict__ a, const float* __restrict__ b,
    ushort* __restrict__ oa, ushort* __restrict__ ob, int n4) {
  const int i = blockIdx.x * 256 + threadIdx.x;
  if (i >= n4) return;
  const float* in = blockIdx.y ? b : a;
  ushort*     out = blockIdx.y ? ob : oa;
  const float4 v = ((const float4*)in)[i];
  ushort4 o;
  o.x = f2bf(v.x); o.y = f2bf(v.y); o.z = f2bf(v.z); o.w = f2bf(v.w);
  ((ushort4*)out)[i] = o;
}

__global__ __launch_bounds__(256) void cast4_bf16(
    const float* __restrict__ a, const float* __restrict__ b,
    const float* __restrict__ c, const float* __restrict__ d,
    ushort* __restrict__ oa, ushort* __restrict__ ob,
    ushort* __restrict__ oc, ushort* __restrict__ od, int n4) {
  const int i = blockIdx.x * 256 + threadIdx.x;
  if (i >= n4) return;
  const float* in; ushort* out;
  switch (blockIdx.y) {
    case 0:  in = a; out = oa; break;
    case 1:  in = b; out = ob; break;
    case 2:  in = c; out = oc; break;
    default: in = d; out = od; break;
  }
  const float4 v = ((const float4*)in)[i];
  ushort4 o;
  o.x = f2bf(v.x); o.y = f2bf(v.y); o.z = f2bf(v.z); o.w = f2bf(v.w);
  ((ushort4*)out)[i] = o;
}

// ---------------- mask tile flags (64x64 granularity) ----------------
__global__ __launch_bounds__(256) void mask_flags(
    const int* __restrict__ mask, int* __restrict__ flags) {
  const int qt = blockIdx.y, kt = blockIdx.x;
  const int t = threadIdx.x;
  const int* p = mask + (size_t)(qt * 64 + (t >> 2)) * 2048 + kt * 64 + (t & 3) * 16;
  int ok = 1;
  #pragma unroll
  for (int i = 0; i < 4; i++) {
    const int4 m = ((const int4*)p)[i];
    ok &= (m.x != 0) & (m.y != 0) & (m.z != 0) & (m.w != 0);
  }
  __shared__ int sok;
  if (t == 0) sok = 1;
  __syncthreads();
  if (!ok) atomicAnd(&sok, 0);
  __syncthreads();
  if (t == 0) flags[qt * 32 + kt] = sok;
}

// ---------------- GEMM: C[M,1024] = A[M,1024] * W[1024,1024]^T ----------------
// 128x128 tile, BK=32, 3-deep counted-vmcnt pipeline, 4 LDS buffers.
// z==0 output is scaled by qscale (used to fold attention scale into Q-proj).
template<bool RESID>
__global__ __launch_bounds__(256) void gemm3(
    const ushort* __restrict__ A0, const ushort* __restrict__ W0, ushort* __restrict__ C0,
    const ushort* __restrict__ A1, const ushort* __restrict__ W1, ushort* __restrict__ C1,
    const ushort* __restrict__ A2, const ushort* __restrict__ W2, ushort* __restrict__ C2,
    float* __restrict__ Cf, const float* __restrict__ resid, float qscale) {
  __shared__ ushort As[4][4096];
  __shared__ ushort Bs[4][4096];
  const int t = threadIdx.x, lane = t & 63, wave = t >> 6;
  const int wr = wave >> 1, wc = wave & 1;
  const int lr = lane & 15, lg = lane >> 4;
  const int brow = blockIdx.y * 128, bcol = blockIdx.x * 128;
  const int z = blockIdx.z;
  const ushort* A = z == 0 ? A0 : (z == 1 ? A1 : A2);
  const ushort* W = z == 0 ? W0 : (z == 1 ? W1 : W2);
  ushort*      C = z == 0 ? C0 : (z == 1 ? C1 : C2);
  const float sc = (z == 0) ? qscale : 1.0f;
  f32x4 acc[4][4] = {};
  const ushort* gA = A + (size_t)(brow + (t >> 2)) * 1024 + (t & 3) * 8;
  const ushort* gB = W + (size_t)(bcol + (t >> 2)) * 1024 + (t & 3) * 8;
  const int woff = wave * 1024;

#define G_ISSUE(S) { \
    char* la = (char*)As + ((S) & 3) * 8192 + woff; \
    char* lb = (char*)Bs + ((S) & 3) * 8192 + woff; \
    const ushort* ap_ = gA + (S) * 32; \
    const ushort* bp_ = gB + (S) * 32; \
    gload16(ap_, la); gload16(ap_ + 64 * 1024, la + 4096); \
    gload16(bp_, lb); gload16(bp_ + 64 * 1024, lb + 4096); }

#define G_COMPUTE(S) { \
    const ushort* as_ = As[(S) & 3]; \
    const ushort* bs_ = Bs[(S) & 3]; \
    bf16x8 af[4], bfr[4]; \
    _Pragma("unroll") for (int i = 0; i < 4; i++) \
      af[i]  = *(const bf16x8*)&as_[(wr*64 + i*16 + lr) * 32 + lg*8]; \
    _Pragma("unroll") for (int i = 0; i < 4; i++) \
      bfr[i] = *(const bf16x8*)&bs_[(wc*64 + i*16 + lr) * 32 + lg*8]; \
    _Pragma("unroll") for (int mi = 0; mi < 4; mi++) \
      _Pragma("unroll") for (int ni = 0; ni < 4; ni++) \
        acc[mi][ni] = __builtin_amdgcn_mfma_f32_16x16x32_bf16(af[mi], bfr[ni], acc[mi][ni], 0, 0, 0); }

  G_ISSUE(0); G_ISSUE(1); G_ISSUE(2);
  for (int s = 0; s < 30; ++s) {
    asm volatile("s_waitcnt vmcnt(8)" ::: "memory");
    __builtin_amdgcn_s_barrier();
    if (s < 29) G_ISSUE(s + 3);
    G_COMPUTE(s);
  }
  asm volatile("s_waitcnt vmcnt(4)" ::: "memory");
  __builtin_amdgcn_s_barrier();
  G_COMPUTE(30);
  asm volatile("s_waitcnt vmcnt(0)" ::: "memory");
  __builtin_amdgcn_s_barrier();
  G_COMPUTE(31);
#undef G_ISSUE
#undef G_COMPUTE

  #pragma unroll
  for (int mi = 0; mi < 4; mi++) {
    #pragma unroll
    for (int ni = 0; ni < 4; ni++) {
      #pragma unroll
      for (int r = 0; r < 4; r++) {
        const size_t row = brow + wr*64 + mi*16 + lg*4 + r;
        const size_t col = bcol + wc*64 + ni*16 + lr;
        if (RESID) Cf[row * 1024 + col] = acc[mi][ni][r] + resid[row * 1024 + col];
        else       C [row * 1024 + col] = f2bf(acc[mi][ni][r] * sc);
      }
    }
  }
}

// ---------------- Flash attention: swapped QK^T, 32x32x16, in-register softmax
// 4 waves x QBLK=32 q-rows; KVBLK=64; 3-buffer K/V pipeline, 1 barrier/tile.
// K LDS: [kv][d] rows 128B, chunk c at row*128 + ((c<<4) ^ ((row&7)<<4)).
// V LDS: 4x16 subtiles, S=(kv>>2)*4+(d>>4) at S*128, read via ds_read_b64_tr_b16.
// Q is PRE-SCALED by 0.125*log2(e) in the Q-projection GEMM.
__global__ __launch_bounds__(256) void flash_attn(
    const ushort* __restrict__ Qp, const ushort* __restrict__ Kp,
    const ushort* __restrict__ Vp, const int* __restrict__ mask,
    const int* __restrict__ tflags, ushort* __restrict__ AO) {
  const int L = 2048;
  const int qb = blockIdx.x, h = blockIdx.y, b = blockIdx.z;
  const int t = threadIdx.x, lane = t & 63, wave = t >> 6;
  const int l31 = lane & 31, hi = lane >> 5;
  __shared__ ushort Ks[3][64 * 64];
  __shared__ ushort Vs[3][64 * 64];
  __shared__ float red[4][32];
  const size_t base = (size_t)b * L * 1024 + h * 64;
  const int qw0 = qb * 128 + wave * 32;

  // Q fragments (B-operand): lane holds q-col = l31, k = kc*16 + hi*8 + j
  bf16x8 qf[4];
  #pragma unroll
  for (int kc = 0; kc < 4; kc++)
    qf[kc] = *(const bf16x8*)(Qp + base + (size_t)(qw0 + l31) * 1024 + kc*16 + hi*8);

  f32x16 accO0 = {0.f}, accO1 = {0.f};
  float m_run = -1e30f, l_run = 0.f;

  // K staging: pre-swizzled global source, linear LDS dest
  const int r3 = (lane >> 3) & 7;
  const int c3 = (lane & 7) ^ r3;
  const ushort* gK = Kp + base + (size_t)(wave*8 + r3) * 1024 + c3 * 8;
  // V staging: subtile-ordered source, linear LDS dest
  const int sv = t >> 3, hv = t & 7;
  const int vkv = (sv >> 2) * 4 + (hv >> 1);
  const int vd  = (sv & 3) * 16 + (hv & 1) * 8;
  const ushort* gV = Vp + base + (size_t)vkv * 1024 + vd;

  const unsigned vbase = lds_addr((const char*)Vs) + hi * 1024 +
                         ((lane >> 4) & 1) * 128 + (lane & 15) * 8;

#define STAGE(TILE, BUF) { \
    char* kb_ = (char*)Ks[BUF] + wave * 1024; \
    const ushort* gk_ = gK + (size_t)(TILE) * 65536; \
    gload16(gk_, kb_); gload16(gk_ + 32*1024, kb_ + 4096); \
    char* vb_ = (char*)Vs[BUF] + wave * 1024; \
    const ushort* gv_ = gV + (size_t)(TILE) * 65536; \
    gload16(gv_, vb_); gload16(gv_ + 32*1024, vb_ + 4096); }

  STAGE(0, 0);
  STAGE(1, 1);
  const int flagBase = (qb * 2 + (wave >> 1)) * 32;

  for (int kvt = 0; kvt < 32; ++kvt) {
    const int buf = kvt % 3;
    if (kvt < 31) { asm volatile("s_waitcnt vmcnt(4)" ::: "memory"); }
    else          { asm volatile("s_waitcnt vmcnt(0)" ::: "memory"); }
    __builtin_amdgcn_s_barrier();
    if (kvt + 2 < 32) { STAGE(kvt + 2, (kvt + 2) % 3); }

    // ---- S^T = K Q^T : lane holds q = l31, 16 kv rows per 32-kv block
    const char* KsB = (const char*)Ks[buf];
    f32x16 accS0 = {0.f}, accS1 = {0.f};
    __builtin_amdgcn_s_setprio(1);
    #pragma unroll
    for (int kc = 0; kc < 4; kc++) {
      const int row0 = l31;
      const bf16x8 kf0 = *(const bf16x8*)(KsB + row0 * 128 +
                          ((kc*32 + hi*16) ^ ((row0 & 7) << 4)));
      accS0 = __builtin_amdgcn_mfma_f32_32x32x16_bf16(kf0, qf[kc], accS0, 0, 0, 0);
      const int row1 = 32 + l31;
      const bf16x8 kf1 = *(const bf16x8*)(KsB + row1 * 128 +
                          ((kc*32 + hi*16) ^ ((row1 & 7) << 4)));
      accS1 = __builtin_amdgcn_mfma_f32_32x32x16_bf16(kf1, qf[kc], accS1, 0, 0, 0);
    }
    __builtin_amdgcn_s_setprio(0);

    // ---- mask (rare path)
    if (tflags[flagBase + kvt] == 0) {
      const size_t mrow = (size_t)(qw0 + l31) * L + kvt * 64;
      #pragma unroll
      for (int r = 0; r < 16; ++r) {
        const int kvr = (r & 3) + 8 * (r >> 2) + 4 * hi;
        if (mask[mrow + kvr] == 0)      accS0[r] = -1e9f;
        if (mask[mrow + 32 + kvr] == 0) accS1[r] = -1e9f;
      }
    }

    // ---- row max (in-register + one permlane swap)
    float mx = fmaxf(accS0[0], accS1[0]);
    #pragma unroll
    for (int r = 1; r < 16; ++r) mx = fmaxf(mx, fmaxf(accS0[r], accS1[r]));
    {
      float tmpm = mx;
      asm("v_permlane32_swap_b32 %0, %1" : "+v"(mx), "+v"(tmpm));
      mx = fmaxf(mx, tmpm);
    }

    // ---- defer-max rescale (rare)
    const bool need = mx > m_run + 8.0f;
    if (__any(need)) {
      const float mnew = need ? mx : m_run;
      const float alpha = exp2f(m_run - mnew);
      red[wave][l31] = alpha;
      #pragma unroll
      for (int r = 0; r < 16; ++r) {
        const float ar = red[wave][(r & 3) + 8 * (r >> 2) + 4 * hi];
        accO0[r] *= ar; accO1[r] *= ar;
      }
      l_run *= alpha;
      m_run = mnew;
    }

    // ---- p = exp2(s - m)
    #pragma unroll
    for (int r = 0; r < 16; ++r) {
      accS0[r] = exp2f(accS0[r] - m_run);
      accS1[r] = exp2f(accS1[r] - m_run);
    }

    // ---- issue V tr-reads early (latency hides under sum + pack)
    const unsigned va = vbase + buf * 8192;
    s16x4 vlo[2][4], vhi[2][4];
    #pragma unroll
    for (int dblk = 0; dblk < 2; dblk++) {
      #pragma unroll
      for (int kc = 0; kc < 4; kc++) {
        asm volatile("ds_read_b64_tr_b16 %0, %2 offset:%3\n\t"
                     "ds_read_b64_tr_b16 %1, %2 offset:%4"
                     : "=v"(vlo[dblk][kc]), "=v"(vhi[dblk][kc])
                     : "v"(va), "i"(kc*2048 + dblk*256), "i"(kc*2048 + dblk*256 + 512)
                     : "memory");
      }
    }

    // ---- row sum
    float sm = accS0[0] + accS1[0];
    #pragma unroll
    for (int r = 1; r < 16; ++r) sm += accS0[r] + accS1[r];
    {
      float tmps = sm;
      asm("v_permlane32_swap_b32 %0, %1" : "+v"(sm), "+v"(tmps));
      sm += tmps;
    }
    l_run += sm;

    // ---- pack P into MFMA A-fragments: 16 cvt_pk + 8 permlane32_swap
    union U8 { uint32_t u[4]; bf16x8 v; };
    bf16x8 pa[4];
    #pragma unroll
    for (int b2 = 0; b2 < 2; b2++) {
      const f32x16& P = b2 ? accS1 : accS0;
      uint32_t t0 = cvtpk(P[0], P[1]),  t1 = cvtpk(P[4], P[5]);
      uint32_t u0 = cvtpk(P[2], P[3]),  u1 = cvtpk(P[6], P[7]);
      asm("v_permlane32_swap_b32 %0, %1" : "+v"(t0), "+v"(t1));
      asm("v_permlane32_swap_b32 %0, %1" : "+v"(u0), "+v"(u1));
      U8 f0; f0.u[0] = t0; f0.u[1] = u0; f0.u[2] = t1; f0.u[3] = u1;
      pa[2*b2] = f0.v;
      uint32_t v0 = cvtpk(P[8], P[9]),   v1 = cvtpk(P[12], P[13]);
      uint32_t w0 = cvtpk(P[10], P[11]), w1 = cvtpk(P[14], P[15]);
      asm("v_permlane32_swap_b32 %0, %1" : "+v"(v0), "+v"(v1));
      asm("v_permlane32_swap_b32 %0, %1" : "+v"(w0), "+v"(w1));
      U8 f1; f1.u[0] = v0; f1.u[1] = w0; f1.u[2] = v1; f1.u[3] = w1;
      pa[2*b2+1] = f1.v;
    }

    // ---- O += P V
    asm volatile("s_waitcnt lgkmcnt(0)" ::: "memory");
    __builtin_amdgcn_sched_barrier(0);
    __builtin_amdgcn_s_setprio(1);
    #pragma unroll
    for (int kc = 0; kc < 4; kc++) {
      const bf16x8 bv0 = __builtin_shufflevector(vlo[0][kc], vhi[0][kc],
                                                 0, 1, 2, 3, 4, 5, 6, 7);
      accO0 = __builtin_amdgcn_mfma_f32_32x32x16_bf16(pa[kc], bv0, accO0, 0, 0, 0);
      const bf16x8 bv1 = __builtin_shufflevector(vlo[1][kc], vhi[1][kc],
                                                 0, 1, 2, 3, 4, 5, 6, 7);
      accO1 = __builtin_amdgcn_mfma_f32_32x32x16_bf16(pa[kc], bv1, accO1, 0, 0, 0);
    }
    __builtin_amdgcn_s_setprio(0);
  }

  // ---- epilogue: redistribute 1/l to C-layout rows, write AO
  red[wave][l31] = 1.0f / l_run;
  #pragma unroll
  for (int r = 0; r < 16; ++r) {
    const int qr = (r & 3) + 8 * (r >> 2) + 4 * hi;
    const float sc = red[wave][qr];
    const size_t row = (size_t)b * L + qw0 + qr;
    AO[row * 1024 + h*64 +      l31] = f2bf(accO0[r] * sc);
    AO[row * 1024 + h*64 + 32 + l31] = f2bf(accO1[r] * sc);
  }
#undef STAGE
}

extern "C" void kernel_launch(void* const* d_in, const int* in_sizes, int n_in,
                              void* d_out, int out_size, void* d_ws, size_t ws_size,
                              hipStream_t stream) {
  const float* q    = (const float*)d_in[0];
  const float* k    = (const float*)d_in[1];
  const float* v    = (const float*)d_in[2];
  const int*   mask = (const int*)d_in[3];
  const float* w_q  = (const float*)d_in[4];
  const float* w_k  = (const float*)d_in[5];
  const float* w_v  = (const float*)d_in[6];
  const float* w_o  = (const float*)d_in[7];
  const float* ln_g = (const float*)d_in[8];
  const float* ln_b = (const float*)d_in[9];
  float* out = (float*)d_out;

  const int M = 4096, D = 1024;
  char* ws = (char*)d_ws;
  const size_t MB = (size_t)1 << 20;
  ushort* qn  = (ushort*)(ws + 0*MB);
  ushort* kb  = (ushort*)(ws + 8*MB);
  ushort* vb  = (ushort*)(ws + 16*MB);
  ushort* wqb = (ushort*)(ws + 24*MB);
  ushort* wkb = (ushort*)(ws + 26*MB);
  ushort* wvb = (ushort*)(ws + 28*MB);
  ushort* wob = (ushort*)(ws + 30*MB);
  ushort* Qp  = (ushort*)(ws + 32*MB);
  ushort* Kp  = (ushort*)(ws + 40*MB);
  ushort* Vp  = (ushort*)(ws + 48*MB);
  ushort* AO  = (ushort*)(ws + 56*MB);
  int* tflags = (int*)(ws + 8*MB);       // reuses kb after QKV GEMM consumed it

  const float QSCALE = 0.125f * 1.44269504089f;   // 1/sqrt(64) * log2(e)

  ln_kernel<<<M, 256, 0, stream>>>(q, ln_g, ln_b, qn);
  const int n4x = M * D / 4, n4w = D * D / 4;
  cast2_bf16<<<dim3((n4x + 255) / 256, 2), 256, 0, stream>>>(k, v, kb, vb, n4x);
  cast4_bf16<<<dim3((n4w + 255) / 256, 4), 256, 0, stream>>>(
      w_q, w_k, w_v, w_o, wqb, wkb, wvb, wob, n4w);

  gemm3<false><<<dim3(8, 32, 3), 256, 0, stream>>>(
      qn, wqb, Qp, kb, wkb, Kp, vb, wvb, Vp, nullptr, nullptr, QSCALE);

  mask_flags<<<dim3(32, 32), 256, 0, stream>>>(mask, tflags);

  flash_attn<<<dim3(16, 16, 2), 256, 0, stream>>>(Qp, Kp, Vp, mask, tflags, AO);

  gemm3<true><<<dim3(8, 32, 1), 256, 0, stream>>>(
      AO, wob, nullptr, nullptr, nullptr, nullptr, nullptr, nullptr, nullptr,
      out, q, 1.0f);
}